// Round 8
// baseline (776.691 us; speedup 1.0000x reference)
//
#include <hip/hip_runtime.h>
#include <hip/hip_bf16.h>

// Chamfer loss via 32x32x16 MFMA, atomic-free, double-buffered.
// predict_pc [B=4,3,N=8192] f32, gt_pc [B,3,N] f32.
// loss = sum_gt min_pred d / B + sum_pred min_gt d / B
//
// m := d^2/2 = on + qn - o.q via bf16 MFMA 32x32x16, split-bf16 (hi+lo ~fp32).
// K=16 fits exactly (records bit-identical to R6/R7-validated):
//   A (opposite row): [-oh(3), -oh(3), -ol(3), -ol(3), onh, onl, 1, 1]
//   B (query col):    [ qh(3),  ql(3),  qh(3),  ql(3), 1, 1, qnh, qnl]
// B-frags are built per-thread straight from coalesced global loads (no q_lds,
// no extra barrier). A-records stream through a double-buffered LDS (stride
// LDR=24 shorts -> conflict-free b128); chunk c+1's global loads issue before
// chunk c's MFMAs (latency hidden), pack+ds_write after, ONE barrier per chunk.
// Fold: 8 v_min3 tree per 1024-elem MFMA. One plain store per query per block
// into partial[(dir*4+b)*ncs+cs][N]; reduce pass min-merges + sqrt + sums.

#define NQ 512      // queries per block (4 waves x 128 cols)
#define OC 256      // opposite points per LDS chunk
#define LDR 24      // record stride in shorts (16 + 8 pad = 48 B)
#define JF 4        // B-frags per wave
#define RBLKS 256

typedef short short8 __attribute__((ext_vector_type(8)));
typedef float f32x16 __attribute__((ext_vector_type(16)));

static __device__ inline unsigned short f2bf(float f) {
    __hip_bfloat16 h = __float2bfloat16(f);
    return *reinterpret_cast<unsigned short*>(&h);
}
static __device__ inline float bf2f(unsigned short u) {
    __hip_bfloat16 h;
    *reinterpret_cast<unsigned short*>(&h) = u;
    return __bfloat162float(h);
}
static __device__ inline void split_bf(float v, unsigned short& hi,
                                       unsigned short& lo) {
    hi = f2bf(v);
    lo = f2bf(v - bf2f(hi));
}
static __device__ inline float min3f(float a, float b, float c) {
    return fminf(fminf(a, b), c);   // clang fuses to v_min3_f32
}

__global__ __launch_bounds__(256, 4) void chamfer_mfma_kernel(
    const float* __restrict__ pred, const float* __restrict__ gt,
    float* __restrict__ partial,   // [(dir*4+b)*ncs+cs][N]
    int N, int ncs, int nchunks, int qtiles)
{
    __align__(16) __shared__ unsigned short o_lds[2][OC * LDR];  // 2 x 12 KB

    int bid = blockIdx.x;
    int cs = bid % ncs;   int t1 = bid / ncs;
    int qt = t1 % qtiles; int t2 = t1 / qtiles;
    int b  = t2 & 3;      int dir = t2 >> 2;

    const float* qpts = dir ? pred : gt;   // dir0: queries=gt (z)
    const float* opts = dir ? gt   : pred; // dir1: queries=pred (z2)
    const float* qb = qpts + (size_t)b * 3 * N;
    const float* ob = opts + (size_t)b * 3 * N;

    int tid = threadIdx.x;
    int lane = tid & 63, w = tid >> 6;
    int col = lane & 31, h = lane >> 5;
    const unsigned short ONE = 0x3F80;

    // ---- B-frags straight from global (coalesced: col consecutive) ----
    short8 bfrag[JF];
    #pragma unroll
    for (int j = 0; j < JF; ++j) {
        int qi = qt * NQ + w * 128 + j * 32 + col;
        float x = qb[qi], y = qb[N + qi], z = qb[2 * N + qi];
        unsigned short hx, lx, hy, ly, hz, lz, nh, nl;
        split_bf(x, hx, lx); split_bf(y, hy, ly); split_bf(z, hz, lz);
        float qn = 0.5f * fmaf(x, x, fmaf(y, y, z * z));
        split_bf(qn, nh, nl);
        short8 bf;
        bf[0] = h ? (short)hz : (short)hx;
        bf[1] = h ? (short)lx : (short)hy;
        bf[2] = h ? (short)ly : (short)hz;
        bf[3] = h ? (short)lz : (short)lx;
        bf[4] = h ? (short)ONE : (short)ly;
        bf[5] = h ? (short)ONE : (short)lz;
        bf[6] = h ? (short)nh : (short)hx;
        bf[7] = h ? (short)nl : (short)hy;
        bfrag[j] = bf;
    }

    int obase = cs * nchunks * OC;

    // pack+write an A-record (negated, R7-exact content) into buffer `buf`
    auto pack_write = [&](int buf, float x, float y, float z) {
        unsigned short hx, lx, hy, ly, hz, lz, nh, nl;
        split_bf(x, hx, lx); split_bf(y, hy, ly); split_bf(z, hz, lz);
        float on = 0.5f * fmaf(x, x, fmaf(y, y, z * z));
        split_bf(on, nh, nl);
        __align__(16) unsigned short r[16] = {
            (unsigned short)(hx ^ 0x8000), (unsigned short)(hy ^ 0x8000),
            (unsigned short)(hz ^ 0x8000), (unsigned short)(hx ^ 0x8000),
            (unsigned short)(hy ^ 0x8000), (unsigned short)(hz ^ 0x8000),
            (unsigned short)(lx ^ 0x8000), (unsigned short)(ly ^ 0x8000),
            (unsigned short)(lz ^ 0x8000), (unsigned short)(lx ^ 0x8000),
            (unsigned short)(ly ^ 0x8000), (unsigned short)(lz ^ 0x8000),
            nh, nl, ONE, ONE};
        unsigned short* dst = o_lds[buf] + tid * LDR;
        *(short8*)(dst + 0) = ((const short8*)r)[0];
        *(short8*)(dst + 8) = ((const short8*)r)[1];
    };

    // prologue: stage chunk 0
    {
        int oi = obase + tid;
        pack_write(0, ob[oi], ob[N + oi], ob[2 * N + oi]);
    }
    __syncthreads();

    float mn[JF] = {3.0e38f, 3.0e38f, 3.0e38f, 3.0e38f};
    const f32x16 zero16 = {0.f};

    for (int c = 0; c < nchunks; ++c) {
        int cur = c & 1;
        // issue next chunk's loads early (latency hides under MFMAs)
        float nx = 0.f, ny = 0.f, nz = 0.f;
        if (c + 1 < nchunks) {
            int oi = obase + (c + 1) * OC + tid;
            nx = ob[oi]; ny = ob[N + oi]; nz = ob[2 * N + oi];
        }

        const unsigned short* ol = o_lds[cur];
        #pragma unroll
        for (int i = 0; i < OC / 32; ++i) {
            short8 af = *(const short8*)(ol + (i * 32 + col) * LDR + h * 8);
            #pragma unroll
            for (int j = 0; j < JF; ++j) {
                f32x16 acc = __builtin_amdgcn_mfma_f32_32x32x16_bf16(
                    af, bfrag[j], zero16, 0, 0, 0);
                float l0 = min3f(acc[0],  acc[1],  acc[2]);
                float l1 = min3f(acc[3],  acc[4],  acc[5]);
                float l2 = min3f(acc[6],  acc[7],  acc[8]);
                float l3 = min3f(acc[9],  acc[10], acc[11]);
                float l4 = min3f(acc[12], acc[13], acc[14]);
                float m0 = min3f(l0, l1, l2);
                float m1 = min3f(l3, l4, acc[15]);
                mn[j] = min3f(m0, m1, mn[j]);
            }
        }

        if (c + 1 < nchunks) pack_write(cur ^ 1, nx, ny, nz);
        __syncthreads();   // next buffer staged; current reads done block-wide
    }

    // fold the two k-half lane groups (rows +4h) of each query column
    #pragma unroll
    for (int j = 0; j < JF; ++j)
        mn[j] = fminf(mn[j], __shfl_xor(mn[j], 32, 64));

    if (lane < 32) {
        float* pp = partial + ((size_t)((dir * 4 + b) * ncs + cs)) * N
                  + qt * NQ + w * 128 + col;
        #pragma unroll
        for (int j = 0; j < JF; ++j) pp[j * 32] = mn[j];
    }
}

__global__ __launch_bounds__(256) void chamfer_reduce1_kernel(
    const float* __restrict__ partial, float* __restrict__ partials2,
    int N, int ncs, int iters)
{
    __shared__ float sdata[256];
    float s = 0.0f;
    for (int k = 0; k < iters; ++k) {
        int L = (blockIdx.x * iters + k) * 256 + threadIdx.x;
        int row = L / N, q = L - row * N;
        const float* pp = partial + (size_t)row * ncs * N + q;
        float v = pp[0];
        for (int cs = 1; cs < ncs; ++cs) v = fminf(v, pp[(size_t)cs * N]);
        s += sqrtf(fmaxf(2.0f * v, 0.0f));   // d = sqrt(2m)
    }
    sdata[threadIdx.x] = s;
    __syncthreads();
    for (int off = 128; off > 0; off >>= 1) {
        if (threadIdx.x < off) sdata[threadIdx.x] += sdata[threadIdx.x + off];
        __syncthreads();
    }
    if (threadIdx.x == 0) partials2[blockIdx.x] = sdata[0];
}

__global__ __launch_bounds__(256) void chamfer_reduce2_kernel(
    const float* __restrict__ partials2, float* __restrict__ out, float inv_b)
{
    __shared__ float sdata[256];
    sdata[threadIdx.x] = partials2[threadIdx.x];
    __syncthreads();
    for (int off = 128; off > 0; off >>= 1) {
        if (threadIdx.x < off) sdata[threadIdx.x] += sdata[threadIdx.x + off];
        __syncthreads();
    }
    if (threadIdx.x == 0) out[0] = sdata[0] * inv_b;
}

extern "C" void kernel_launch(void* const* d_in, const int* in_sizes, int n_in,
                              void* d_out, int out_size, void* d_ws, size_t ws_size,
                              hipStream_t stream) {
    const float* pred = (const float*)d_in[0];
    const float* gt   = (const float*)d_in[1];
    const int B = 4, D = 3;
    const int N = in_sizes[0] / (B * D);   // 8192

    // strip count bounded by workspace: bytes = 2*B*ncs*N*4 + RBLKS*4
    int ncs = 8;
    while (ncs > 1 &&
           ws_size < (size_t)2 * B * ncs * N * sizeof(float) + RBLKS * sizeof(float))
        ncs >>= 1;

    float* partial   = (float*)d_ws;                       // [2*B*ncs][N]
    float* partials2 = partial + (size_t)2 * B * ncs * N;  // [RBLKS]

    int qtiles  = N / NQ;            // 16
    int nchunks = N / (ncs * OC);    // 4 at ncs=8
    dim3 grid1(2 * B * qtiles * ncs);  // 1024 at ncs=8
    chamfer_mfma_kernel<<<grid1, dim3(256), 0, stream>>>(
        pred, gt, partial, N, ncs, nchunks, qtiles);

    int iters = (2 * B * N) / (RBLKS * 256);   // 1
    chamfer_reduce1_kernel<<<dim3(RBLKS), dim3(256), 0, stream>>>(
        partial, partials2, N, ncs, iters);
    chamfer_reduce2_kernel<<<dim3(1), dim3(256), 0, stream>>>(
        partials2, (float*)d_out, 1.0f / B);
}

// Round 9
// 43.276 us; speedup vs baseline: 17.9473x; 17.9473x over previous
//
#include <hip/hip_runtime.h>
#include <hip/hip_bf16.h>

// Chamfer loss via 32x32x16 MFMA, LDS-free / barrier-free main loop.
// predict_pc [B=4,3,N=8192] f32, gt_pc [B,3,N] f32.
// loss = sum_gt min_pred d / B + sum_pred min_gt d / B
//
// m := d^2/2 = on + qn - o.q via bf16 MFMA 32x32x16, split-bf16 (hi+lo ~fp32).
// Records (16 shorts = 32 B, content bit-identical to R6/R7-validated):
//   A (opposite): [-oh(3), -oh(3), -ol(3), -ol(3), onh, onl, 1, 1]
//   B (query):    [ qh(3),  ql(3),  qh(3),  ql(3), 1, 1, qnh, qnl]
// A pack kernel precomputes both record forms for both sides into d_ws
// (4 MB, L2-resident). The main kernel loads each lane's fragment as ONE
// 16 B global load (record[...] + h*8 shorts): no LDS, no barriers, no
// in-loop packing (R8's spill trap eliminated). Per i-step: 1 load + 4 MFMA
// + 8-min3 tree x4. One plain store per query per block into
// partial[(dir*4+b)*ncs+cs][N]; reduce pass min-merges + sqrt + sums.
// cs = bid%ncs (fast index) -> same-strip blocks XCD-pinned for L2 locality.

#define NQ 512      // queries per block (4 waves x 128 cols)
#define JF 4        // B-frags per wave
#define RBLKS 256

typedef short short8 __attribute__((ext_vector_type(8)));
typedef float f32x16 __attribute__((ext_vector_type(16)));

static __device__ inline unsigned short f2bf(float f) {
    __hip_bfloat16 h = __float2bfloat16(f);
    return *reinterpret_cast<unsigned short*>(&h);
}
static __device__ inline float bf2f(unsigned short u) {
    __hip_bfloat16 h;
    *reinterpret_cast<unsigned short*>(&h) = u;
    return __bfloat162float(h);
}
static __device__ inline void split_bf(float v, unsigned short& hi,
                                       unsigned short& lo) {
    hi = f2bf(v);
    lo = f2bf(v - bf2f(hi));
}
static __device__ inline float min3f(float a, float b, float c) {
    return fminf(fminf(a, b), c);   // clang fuses to v_min3_f32
}

// pack both record forms for every point of both sides
__global__ __launch_bounds__(256) void chamfer_pack_kernel(
    const float* __restrict__ pred, const float* __restrict__ gt,
    unsigned short* __restrict__ bufA, unsigned short* __restrict__ bufB,
    int N)
{
    int t = blockIdx.x * 256 + threadIdx.x;   // over 2*4*N points
    int n = t % N, sb = t / N;                 // sb = side*4 + b
    const float* src = ((sb >> 2) ? gt : pred) + (size_t)(sb & 3) * 3 * N;
    float x = src[n], y = src[N + n], z = src[2 * N + n];

    unsigned short hx, lx, hy, ly, hz, lz, nh, nl;
    split_bf(x, hx, lx); split_bf(y, hy, ly); split_bf(z, hz, lz);
    float pn = 0.5f * fmaf(x, x, fmaf(y, y, z * z));
    split_bf(pn, nh, nl);
    const short ONE = 0x3F80;
    #define NG(u) ((short)((u) ^ 0x8000))

    short8 a0 = {NG(hx), NG(hy), NG(hz), NG(hx), NG(hy), NG(hz), NG(lx), NG(ly)};
    short8 a1 = {NG(lz), NG(lx), NG(ly), NG(lz), (short)nh, (short)nl, ONE, ONE};
    short8 b0 = {(short)hx, (short)hy, (short)hz, (short)lx, (short)ly,
                 (short)lz, (short)hx, (short)hy};
    short8 b1 = {(short)hz, (short)lx, (short)ly, (short)lz, ONE, ONE,
                 (short)nh, (short)nl};
    #undef NG

    short8* da = (short8*)(bufA + (size_t)t * 16);
    da[0] = a0; da[1] = a1;
    short8* db = (short8*)(bufB + (size_t)t * 16);
    db[0] = b0; db[1] = b1;
}

__global__ __launch_bounds__(256) void chamfer_mfma_kernel(
    const unsigned short* __restrict__ bufA,
    const unsigned short* __restrict__ bufB,
    float* __restrict__ partial,   // [(dir*4+b)*ncs+cs][N]
    int N, int ncs, int qtiles)
{
    int bid = blockIdx.x;
    int cs = bid % ncs;   int t1 = bid / ncs;
    int qt = t1 % qtiles; int t2 = t1 / qtiles;
    int b  = t2 & 3;      int dir = t2 >> 2;
    int sq = dir ? 0 : 1, so = 1 - sq;  // query side / opposite side

    int tid = threadIdx.x;
    int lane = tid & 63, w = tid >> 6;
    int col = lane & 31, h = lane >> 5;

    // B-frags: one 16 B load each, registers for the whole kernel
    const unsigned short* qbase =
        bufB + ((size_t)(sq * 4 + b) * N + qt * NQ + w * 128 + col) * 16 + h * 8;
    short8 bfrag[JF];
    #pragma unroll
    for (int j = 0; j < JF; ++j)
        bfrag[j] = *(const short8*)(qbase + j * 32 * 16);

    int strip = N / ncs;   // 1024 opposite points at ncs=8
    const unsigned short* abase =
        bufA + ((size_t)(so * 4 + b) * N + cs * strip + col) * 16 + h * 8;

    float mn[JF] = {3.0e38f, 3.0e38f, 3.0e38f, 3.0e38f};
    const f32x16 zero16 = {0.f};

    #pragma unroll 4
    for (int i = 0; i < strip / 32; ++i) {
        short8 af = *(const short8*)(abase + (size_t)i * 32 * 16);
        #pragma unroll
        for (int j = 0; j < JF; ++j) {
            f32x16 acc = __builtin_amdgcn_mfma_f32_32x32x16_bf16(
                af, bfrag[j], zero16, 0, 0, 0);
            float l0 = min3f(acc[0],  acc[1],  acc[2]);
            float l1 = min3f(acc[3],  acc[4],  acc[5]);
            float l2 = min3f(acc[6],  acc[7],  acc[8]);
            float l3 = min3f(acc[9],  acc[10], acc[11]);
            float l4 = min3f(acc[12], acc[13], acc[14]);
            float m0 = min3f(l0, l1, l2);
            float m1 = min3f(l3, l4, acc[15]);
            mn[j] = min3f(m0, m1, mn[j]);
        }
    }

    // fold the two k-half lane groups (rows +4h) of each query column
    #pragma unroll
    for (int j = 0; j < JF; ++j)
        mn[j] = fminf(mn[j], __shfl_xor(mn[j], 32, 64));

    if (lane < 32) {
        float* pp = partial + ((size_t)((dir * 4 + b) * ncs + cs)) * N
                  + qt * NQ + w * 128 + col;
        #pragma unroll
        for (int j = 0; j < JF; ++j) pp[j * 32] = mn[j];
    }
}

__global__ __launch_bounds__(256) void chamfer_reduce1_kernel(
    const float* __restrict__ partial, float* __restrict__ partials2,
    int N, int ncs)
{
    __shared__ float sdata[256];
    int L = blockIdx.x * 256 + threadIdx.x;   // over 2*B*N queries
    int row = L / N, q = L - row * N;
    const float* pp = partial + (size_t)row * ncs * N + q;
    float v = pp[0];
    for (int cs = 1; cs < ncs; ++cs) v = fminf(v, pp[(size_t)cs * N]);
    float s = sqrtf(fmaxf(2.0f * v, 0.0f));   // d = sqrt(2m)
    sdata[threadIdx.x] = s;
    __syncthreads();
    for (int off = 128; off > 0; off >>= 1) {
        if (threadIdx.x < off) sdata[threadIdx.x] += sdata[threadIdx.x + off];
        __syncthreads();
    }
    if (threadIdx.x == 0) partials2[blockIdx.x] = sdata[0];
}

__global__ __launch_bounds__(256) void chamfer_reduce2_kernel(
    const float* __restrict__ partials2, float* __restrict__ out, float inv_b)
{
    __shared__ float sdata[256];
    sdata[threadIdx.x] = partials2[threadIdx.x];
    __syncthreads();
    for (int off = 128; off > 0; off >>= 1) {
        if (threadIdx.x < off) sdata[threadIdx.x] += sdata[threadIdx.x + off];
        __syncthreads();
    }
    if (threadIdx.x == 0) out[0] = sdata[0] * inv_b;
}

extern "C" void kernel_launch(void* const* d_in, const int* in_sizes, int n_in,
                              void* d_out, int out_size, void* d_ws, size_t ws_size,
                              hipStream_t stream) {
    const float* pred = (const float*)d_in[0];
    const float* gt   = (const float*)d_in[1];
    const int B = 4, D = 3;
    const int N = in_sizes[0] / (B * D);   // 8192

    // workspace: bufA (2*4*N recs) + bufB (same) + partial + partials2
    unsigned short* bufA = (unsigned short*)d_ws;
    unsigned short* bufB = bufA + (size_t)2 * 4 * N * 16;
    size_t buf_bytes = (size_t)2 * 2 * 4 * N * 16 * sizeof(unsigned short);

    int ncs = 8;
    while (ncs > 1 &&
           ws_size < buf_bytes + (size_t)2 * B * ncs * N * sizeof(float)
                     + RBLKS * sizeof(float))
        ncs >>= 1;

    float* partial   = (float*)((char*)d_ws + buf_bytes);  // [2*B*ncs][N]
    float* partials2 = partial + (size_t)2 * B * ncs * N;  // [RBLKS]

    chamfer_pack_kernel<<<dim3(2 * B * N / 256), dim3(256), 0, stream>>>(
        pred, gt, bufA, bufB, N);

    int qtiles = N / NQ;               // 16
    dim3 grid1(2 * B * qtiles * ncs);  // 1024 at ncs=8
    chamfer_mfma_kernel<<<grid1, dim3(256), 0, stream>>>(
        bufA, bufB, partial, N, ncs, qtiles);

    chamfer_reduce1_kernel<<<dim3(RBLKS), dim3(256), 0, stream>>>(
        partial, partials2, N, ncs);
    chamfer_reduce2_kernel<<<dim3(1), dim3(256), 0, stream>>>(
        partials2, (float*)d_out, 1.0f / B);
}